// Round 8
// baseline (1224.888 us; speedup 1.0000x reference)
//
#include <hip/hip_runtime.h>

typedef unsigned short u16;
typedef __attribute__((ext_vector_type(8))) unsigned short ushort8;
typedef __attribute__((ext_vector_type(4))) unsigned short ushort4v;
typedef __attribute__((ext_vector_type(8))) short bf16x8;
typedef __attribute__((ext_vector_type(4))) float f32x4;

#define LB    2048
#define DIM   1024
#define NCAT  5248
#define MROWS 8192
#define G     16
#define NG    (LB / G)

__device__ __forceinline__ float b2f(u16 u) {
    unsigned int x = ((unsigned int)u) << 16;
    return __builtin_bit_cast(float, x);
}
__device__ __forceinline__ u16 f2b(float f) {
    unsigned int u = __builtin_bit_cast(unsigned int, f);
    u = u + 0x7FFFu + ((u >> 16) & 1u);
    return (u16)(u >> 16);
}
__device__ __forceinline__ float sigm(float x) { return 1.0f / (1.0f + __expf(-x)); }

// DPP cross-lane add: x + x[lane ^ pattern], full-rate VALU.
template <int CTRL>
__device__ __forceinline__ float dpp_addf(float x) {
    int y = __builtin_amdgcn_update_dpp(0, __builtin_bit_cast(int, x), CTRL, 0xF, 0xF, true);
    return x + __builtin_bit_cast(float, y);
}
__device__ __forceinline__ float sum8_dpp(float x) {
    x = dpp_addf<0xB1>(x);   // xor 1
    x = dpp_addf<0x4E>(x);   // xor 2
    x = dpp_addf<0x141>(x);  // xor 4 (row_half_mirror)
    return x;
}

// async global->LDS, 16B per lane; LDS dest = wave-uniform base + lane*16.
__device__ __forceinline__ void gload_lds16(const u16* g, u16* l) {
    __builtin_amdgcn_global_load_lds((const __attribute__((address_space(1))) void*)g,
                                     (__attribute__((address_space(3))) void*)l, 16, 0, 0);
}

// ---------------- elementwise prep ----------------
__global__ void f32_to_bf16(const float* __restrict__ src, u16* __restrict__ dst, int n) {
    int i = (blockIdx.x * 256 + threadIdx.x) * 4;
    if (i >= n) return;
    float4 v = *(const float4*)(src + i);
    ushort4v u;
    u[0] = f2b(v.x); u[1] = f2b(v.y); u[2] = f2b(v.z); u[3] = f2b(v.w);
    *(ushort4v*)(dst + i) = u;
}

// src [1024, cols] f32  ->  dst[c*1024 + r] bf16   (grid: (cols, 4), block 256)
__global__ void transpose_f32_bf16(const float* __restrict__ src, u16* __restrict__ dst, int cols) {
    const int cidx = blockIdx.x;
    const int r = blockIdx.y * 256 + threadIdx.x;
    dst[(size_t)cidx * 1024 + r] = f2b(src[(size_t)r * cols + cidx]);
}

__global__ void fill_zero_u16(u16* __restrict__ dst, int n) {
    int i = blockIdx.x * 256 + threadIdx.x;
    if (i < n) dst[i] = 0;
}

// ---------------- bf16 MFMA GEMM (m97 structure):  C[M,N] = A[M,K] * Bt[N,K]^T ----------------
// Linear LDS tiles [128][32] u16 (no padding: global_load_lds writes base+lane*16).
template <int OUT_IS_F32>
__global__ __launch_bounds__(256) void gemm_bt(const u16* __restrict__ A,
                                               const u16* __restrict__ Bt,
                                               void* __restrict__ Cv,
                                               int M, int N, int K) {
    __shared__ u16 lds_a[128 * 32];
    __shared__ u16 lds_b[128 * 32];
    const int tid = threadIdx.x;
    const int m0 = blockIdx.y * 128;
    const int n0 = blockIdx.x * 128;
    const int w = tid >> 6;
    const int l = tid & 63;
    const int wm = w >> 1, wn = w & 1;
    const int lr = l & 15, kg = l >> 4;

    f32x4 acc[4][4];
#pragma unroll
    for (int m = 0; m < 4; ++m)
#pragma unroll
        for (int n = 0; n < 4; ++n)
            acc[m][n] = f32x4{0.f, 0.f, 0.f, 0.f};

    // staging geometry: wave w stages rows [w*32, w*32+32); per load: 16 rows,
    // lane i -> row i>>2, col chunk (i&3)*8  (16B per lane, 64B per row).
    const int srow = (l >> 2);
    const int scol = (l & 3) * 8;

    for (int kt = 0; kt < K; kt += 32) {
#pragma unroll
        for (int ld = 0; ld < 2; ++ld) {
            const int row = w * 32 + ld * 16 + srow;
            gload_lds16(A + (size_t)(m0 + row) * K + kt + scol, &lds_a[(w * 32 + ld * 16) * 32]);
            gload_lds16(Bt + (size_t)(n0 + row) * K + kt + scol, &lds_b[(w * 32 + ld * 16) * 32]);
        }
        __syncthreads();
        bf16x8 af[4], bfv[4];
#pragma unroll
        for (int m = 0; m < 4; ++m)
            af[m] = *(const bf16x8*)&lds_a[(wm * 64 + m * 16 + lr) * 32 + kg * 8];
#pragma unroll
        for (int n = 0; n < 4; ++n)
            bfv[n] = *(const bf16x8*)&lds_b[(wn * 64 + n * 16 + lr) * 32 + kg * 8];
#pragma unroll
        for (int m = 0; m < 4; ++m)
#pragma unroll
            for (int n = 0; n < 4; ++n)
                acc[m][n] = __builtin_amdgcn_mfma_f32_16x16x32_bf16(af[m], bfv[n], acc[m][n], 0, 0, 0);
        __syncthreads();
    }

#pragma unroll
    for (int m = 0; m < 4; ++m) {
#pragma unroll
        for (int n = 0; n < 4; ++n) {
            const int col = n0 + wn * 64 + n * 16 + lr;
#pragma unroll
            for (int j = 0; j < 4; ++j) {
                const int row = m0 + wm * 64 + m * 16 + kg * 4 + j;
                if (OUT_IS_F32)
                    ((float*)Cv)[(size_t)row * N + col] = acc[m][n][j];
                else
                    ((u16*)Cv)[(size_t)row * N + col] = f2b(acc[m][n][j]);
            }
        }
    }
}

// ---------------- causal depthwise conv (K=4) + bias + SiLU (+scale) ----------------
__global__ __launch_bounds__(256) void conv_silu(const u16* __restrict__ pre,
                                                 u16* __restrict__ dst,
                                                 const float* __restrict__ w,
                                                 const float* __restrict__ bias,
                                                 float scale, int col_off) {
    const int row = blockIdx.x;       // b*L + l
    const int l = row & (LB - 1);
    const int ch = threadIdx.x * 4;
    const float4* wv = (const float4*)(w + ch * 4);
    float wt[4][4];
#pragma unroll
    for (int c = 0; c < 4; ++c) {
        float4 t = wv[c];
        wt[c][0] = t.x; wt[c][1] = t.y; wt[c][2] = t.z; wt[c][3] = t.w;
    }
    float acc[4] = {bias[ch + 0], bias[ch + 1], bias[ch + 2], bias[ch + 3]};
#pragma unroll
    for (int dd = 0; dd < 4; ++dd) {
        if (l - 3 + dd >= 0) {
            ushort4v vv = *(const ushort4v*)(pre + (size_t)(row - 3 + dd) * NCAT + col_off + ch);
#pragma unroll
            for (int c = 0; c < 4; ++c) acc[c] += b2f(vv[c]) * wt[c][dd];
        }
    }
    ushort4v outv;
#pragma unroll
    for (int c = 0; c < 4; ++c) {
        float a = acc[c];
        outv[c] = f2b(a * sigm(a) * scale);
    }
    *(ushort4v*)(dst + (size_t)row * DIM + ch) = outv;
}

// ---------------- sequential delta-rule scan: 2 scans per thread ----------------
// 128 blocks, 128 threads. Block handles (b,h) and a PAIR of 16-row v-chunks
// (32 channels). Thread (r=tid>>3, c=tid&7) owns S_A[v0+r][c*16..+16] and
// S_B[v0+16+r][c*16..+16]: two independent chains overlap each other's stalls;
// k/q fragments + conversions are shared.
__global__ __launch_bounds__(128) void scan_kernel(const u16* __restrict__ qb,
                                                   const u16* __restrict__ kb,
                                                   const u16* __restrict__ vb,
                                                   const u16* __restrict__ pre,
                                                   const float* __restrict__ ba,
                                                   const float* __restrict__ bb,
                                                   float* __restrict__ o) {
    // XCD swizzle: XCD = blockIdx % 8; the 4 blocks sharing (b,h) k/q sit on one XCD.
    const int bid = blockIdx.x;                 // 0..127
    const int xcd = bid & 7;
    const int inner = bid >> 3;                 // 0..15
    const int bh = xcd * 4 + (inner >> 2);      // 0..31
    const int vp = inner & 3;                   // 0..3  (pair of v-chunks)
    const int h = bh & 7;
    const int b = bh >> 3;

    const int tid = threadIdx.x;
    const int r = tid >> 3;     // 0..15
    const int c = tid & 7;      // 0..7
    const int k0 = c * 16;
    const int v0 = vp * 32;
    const size_t row0 = (size_t)b * LB;

    __shared__ u16 k_lds[2][G][128];
    __shared__ u16 q_lds[2][G][128];
    __shared__ float v_ldsf[2][G][32];
    __shared__ float a_ldsf[2][G][32];   // sigmoid applied
    __shared__ float b_ldsf[2][G];       // sigmoid applied

    const float bbv = bb[h];

    // staging roles
    const int st_t = tid >> 3, st_c = tid & 7;                 // k/q: all 128 threads
    const u16* kgp = kb + row0 * DIM + h * 128 + st_c * 16;
    const u16* qgp = qb + row0 * DIM + h * 128 + st_c * 16;
    const int vt = tid >> 2, vc4 = tid & 3;                    // v: tid<64
    const u16* vgp = vb + row0 * DIM + h * 128 + v0 + vc4 * 8;
    const int aidx = tid - 64, at = aidx >> 2, ac4 = aidx & 3; // a: tid>=64
    const u16* agp = pre + row0 * NCAT + 3072 + h * 128 + v0 + ac4 * 8;
    const u16* bgp = pre + row0 * NCAT + 5120 + h;             // beta: tid<16
    float* op = o + row0 * DIM + h * 128 + v0 + r;

    float baf[8];
    if (tid >= 64) {
#pragma unroll
        for (int j = 0; j < 8; ++j) baf[j] = ba[h * 128 + v0 + ac4 * 8 + j];
    }

    ushort8 kst0, kst1, qst0, qst1, vst, ast;
    u16 bst;
    ushort8 kn0, kn1, qn0, qn1;
    float vAn, vBn, aAn, aBn, bnf;

#define STAGE_LOAD(gl) do {                                                       \
        const size_t rk = (size_t)((gl) * G + st_t) * DIM;                        \
        kst0 = *(const ushort8*)(kgp + rk);                                       \
        kst1 = *(const ushort8*)(kgp + rk + 8);                                   \
        qst0 = *(const ushort8*)(qgp + rk);                                       \
        qst1 = *(const ushort8*)(qgp + rk + 8);                                   \
        if (tid < 64) {                                                           \
            vst = *(const ushort8*)(vgp + (size_t)((gl) * G + vt) * DIM);         \
        } else {                                                                  \
            ast = *(const ushort8*)(agp + (size_t)((gl) * G + at) * NCAT);        \
        }                                                                         \
        if (tid < 16) bst = bgp[(size_t)((gl) * G + tid) * NCAT];                 \
    } while (0)

#define STAGE_WRITE(bufi) do {                                                    \
        *(ushort8*)&k_lds[bufi][st_t][st_c * 16] = kst0;                          \
        *(ushort8*)&k_lds[bufi][st_t][st_c * 16 + 8] = kst1;                      \
        *(ushort8*)&q_lds[bufi][st_t][st_c * 16] = qst0;                          \
        *(ushort8*)&q_lds[bufi][st_t][st_c * 16 + 8] = qst1;                      \
        if (tid < 64) {                                                           \
            float* d = &v_ldsf[bufi][vt][vc4 * 8];                                \
            _Pragma("unroll") for (int j = 0; j < 8; ++j) d[j] = b2f(vst[j]);     \
        } else {                                                                  \
            float* d = &a_ldsf[bufi][at][ac4 * 8];                                \
            _Pragma("unroll") for (int j = 0; j < 8; ++j) d[j] = sigm(b2f(ast[j]) + baf[j]); \
        }                                                                         \
        if (tid < 16) b_ldsf[bufi][tid] = sigm(b2f(bst) + bbv);                   \
    } while (0)

#define PREFETCH(bufi, tt) do {                                                   \
        kn0 = *(const ushort8*)&k_lds[bufi][tt][k0];                              \
        kn1 = *(const ushort8*)&k_lds[bufi][tt][k0 + 8];                          \
        qn0 = *(const ushort8*)&q_lds[bufi][tt][k0];                              \
        qn1 = *(const ushort8*)&q_lds[bufi][tt][k0 + 8];                          \
        vAn = v_ldsf[bufi][tt][r];  vBn = v_ldsf[bufi][tt][16 + r];               \
        aAn = a_ldsf[bufi][tt][r];  aBn = a_ldsf[bufi][tt][16 + r];               \
        bnf = b_ldsf[bufi][tt];                                                   \
    } while (0)

    float SA[16], SB[16];
#pragma unroll
    for (int j = 0; j < 16; ++j) { SA[j] = 0.f; SB[j] = 0.f; }

    STAGE_LOAD(0);
    STAGE_WRITE(0);
    __syncthreads();
    PREFETCH(0, 0);

    for (int g = 0; g < NG; ++g) {
        const int buf = g & 1;
        const int gn = (g + 1 < NG) ? g + 1 : g;
        STAGE_LOAD(gn);

#pragma unroll
        for (int t = 0; t < G; ++t) {
            const ushort8 kc0 = kn0, kc1 = kn1, qc0 = qn0, qc1 = qn1;
            const float vA = vAn, vB = vBn, aA = aAn, aB = aBn, bt_ = bnf;
            if (t < G - 1) PREFETCH(buf, t + 1);

            float kf[16], qf[16];
#pragma unroll
            for (int j = 0; j < 8; ++j) {
                kf[j] = b2f(kc0[j]); kf[8 + j] = b2f(kc1[j]);
                qf[j] = b2f(qc0[j]); qf[8 + j] = b2f(qc1[j]);
            }

            // err partials for both scans (independent chains)
            float eA0 = 0.f, eA1 = 0.f, eA2 = 0.f, eA3 = 0.f;
            float eB0 = 0.f, eB1 = 0.f, eB2 = 0.f, eB3 = 0.f;
#pragma unroll
            for (int j = 0; j < 4; ++j) {
                eA0 += SA[j] * kf[j];           eB0 += SB[j] * kf[j];
                eA1 += SA[4 + j] * kf[4 + j];   eB1 += SB[4 + j] * kf[4 + j];
                eA2 += SA[8 + j] * kf[8 + j];   eB2 += SB[8 + j] * kf[8 + j];
                eA3 += SA[12 + j] * kf[12 + j]; eB3 += SB[12 + j] * kf[12 + j];
            }
            float eA = sum8_dpp((eA0 + eA1) + (eA2 + eA3));
            float eB = sum8_dpp((eB0 + eB1) + (eB2 + eB3));
            const float beA = bt_ * (eA - vA);
            const float beB = bt_ * (eB - vB);

            float pA0 = 0.f, pA1 = 0.f, pA2 = 0.f, pA3 = 0.f;
            float pB0 = 0.f, pB1 = 0.f, pB2 = 0.f, pB3 = 0.f;
#pragma unroll
            for (int j = 0; j < 4; ++j) {
                SA[j] = aA * SA[j] - beA * kf[j];                 pA0 += SA[j] * qf[j];
                SB[j] = aB * SB[j] - beB * kf[j];                 pB0 += SB[j] * qf[j];
                SA[4 + j] = aA * SA[4 + j] - beA * kf[4 + j];     pA1 += SA[4 + j] * qf[4 + j];
                SB[4 + j] = aB * SB[4 + j] - beB * kf[4 + j];     pB1 += SB[4 + j] * qf[4 + j];
                SA[8 + j] = aA * SA[8 + j] - beA * kf[8 + j];     pA2 += SA[8 + j] * qf[8 + j];
                SB[8 + j] = aB * SB[8 + j] - beB * kf[8 + j];     pB2 += SB[8 + j] * qf[8 + j];
                SA[12 + j] = aA * SA[12 + j] - beA * kf[12 + j];  pA3 += SA[12 + j] * qf[12 + j];
                SB[12 + j] = aB * SB[12 + j] - beB * kf[12 + j];  pB3 += SB[12 + j] * qf[12 + j];
            }
            float poA = sum8_dpp((pA0 + pA1) + (pA2 + pA3));
            float poB = sum8_dpp((pB0 + pB1) + (pB2 + pB3));
            if (c == 0) {
                op[(size_t)(g * G + t) * DIM] = poA;
                op[(size_t)(g * G + t) * DIM + 16] = poB;
            }
        }

        STAGE_WRITE(buf ^ 1);
        __syncthreads();
        PREFETCH(buf ^ 1, 0);
    }
#undef STAGE_LOAD
#undef STAGE_WRITE
#undef PREFETCH
}

// ---------------- LayerNorm(DV) + sigmoid gate -> bf16 ----------------
__global__ __launch_bounds__(256) void ln_gate(const float* __restrict__ o,
                                               const u16* __restrict__ pre,
                                               const float* __restrict__ ln_g,
                                               const float* __restrict__ ln_b,
                                               u16* __restrict__ o2) {
    const int row = blockIdx.x;
    const int tid = threadIdx.x;
    const int h = tid >> 5;
    const int lg = tid & 31;
    const int d0 = lg * 4;
    float4 x = *(const float4*)(o + (size_t)row * DIM + h * 128 + d0);
    float s = x.x + x.y + x.z + x.w;
    float ss = x.x * x.x + x.y * x.y + x.z * x.z + x.w * x.w;
#pragma unroll
    for (int m = 1; m <= 16; m <<= 1) {
        s += __shfl_xor(s, m);
        ss += __shfl_xor(ss, m);
    }
    const float mu = s * (1.f / 128.f);
    const float var = ss * (1.f / 128.f) - mu * mu;
    const float inv = rsqrtf(var + 1e-5f);
    ushort4v gp = *(const ushort4v*)(pre + (size_t)row * NCAT + 4096 + h * 128 + d0);
    float4 lg4 = *(const float4*)(ln_g + d0);
    float4 lb4 = *(const float4*)(ln_b + d0);
    float xv[4] = {x.x, x.y, x.z, x.w};
    float gv[4] = {lg4.x, lg4.y, lg4.z, lg4.w};
    float bv[4] = {lb4.x, lb4.y, lb4.z, lb4.w};
    ushort4v outv;
#pragma unroll
    for (int q = 0; q < 4; ++q) {
        float y = (xv[q] - mu) * inv * gv[q] + bv[q];
        y *= sigm(b2f(gp[q]));
        outv[q] = f2b(y);
    }
    *(ushort4v*)(o2 + (size_t)row * DIM + h * 128 + d0) = outv;
}

extern "C" void kernel_launch(void* const* d_in, const int* in_sizes, int n_in,
                              void* d_out, int out_size, void* d_ws, size_t ws_size,
                              hipStream_t stream) {
    const float* x   = (const float*)d_in[0];
    const float* Wq  = (const float*)d_in[1];
    const float* Wk  = (const float*)d_in[2];
    const float* Wv  = (const float*)d_in[3];
    const float* Wa  = (const float*)d_in[4];
    const float* ba  = (const float*)d_in[5];
    const float* Wb  = (const float*)d_in[6];
    const float* bb  = (const float*)d_in[7];
    const float* Wg  = (const float*)d_in[8];
    const float* Wo  = (const float*)d_in[9];
    const float* cqw = (const float*)d_in[10];
    const float* cqb = (const float*)d_in[11];
    const float* ckw = (const float*)d_in[12];
    const float* ckb = (const float*)d_in[13];
    const float* cvw = (const float*)d_in[14];
    const float* cvb = (const float*)d_in[15];
    const float* lng = (const float*)d_in[16];
    const float* lnb = (const float*)d_in[17];

    const size_t NEED = (size_t)MROWS * DIM * 2
                      + (size_t)NCAT * DIM * 2
                      + (size_t)DIM * DIM * 2
                      + (size_t)MROWS * NCAT * 2
                      + 3 * (size_t)MROWS * DIM * 2
                      + (size_t)MROWS * DIM * 4
                      + (size_t)MROWS * DIM * 2;
    if (ws_size < NEED) return;

    char* p = (char*)d_ws;
    u16* x_bf  = (u16*)p; p += (size_t)MROWS * DIM * 2;
    u16* wcatT = (u16*)p; p += (size_t)NCAT * DIM * 2;
    u16* woT   = (u16*)p; p += (size_t)DIM * DIM * 2;
    u16* pre   = (u16*)p; p += (size_t)MROWS * NCAT * 2;
    u16* qbuf  = (u16*)p; p += (size_t)MROWS * DIM * 2;
    u16* kbuf  = (u16*)p; p += (size_t)MROWS * DIM * 2;
    u16* vbuf  = (u16*)p; p += (size_t)MROWS * DIM * 2;
    float* obuf = (float*)p; p += (size_t)MROWS * DIM * 4;
    u16* o2buf = (u16*)p;

    f32_to_bf16<<<MROWS * DIM / 1024, 256, 0, stream>>>(x, x_bf, MROWS * DIM);
    transpose_f32_bf16<<<dim3(1024, 4), 256, 0, stream>>>(Wq, wcatT + 0 * 1024 * 1024, 1024);
    transpose_f32_bf16<<<dim3(1024, 4), 256, 0, stream>>>(Wk, wcatT + 1 * 1024 * 1024, 1024);
    transpose_f32_bf16<<<dim3(1024, 4), 256, 0, stream>>>(Wv, wcatT + 2 * 1024 * 1024, 1024);
    transpose_f32_bf16<<<dim3(1024, 4), 256, 0, stream>>>(Wa, wcatT + 3 * 1024 * 1024, 1024);
    transpose_f32_bf16<<<dim3(1024, 4), 256, 0, stream>>>(Wg, wcatT + 4 * 1024 * 1024, 1024);
    transpose_f32_bf16<<<dim3(8, 4), 256, 0, stream>>>(Wb, wcatT + (size_t)5120 * 1024, 8);
    transpose_f32_bf16<<<dim3(1024, 4), 256, 0, stream>>>(Wo, woT, 1024);
    fill_zero_u16<<<(120 * 1024 + 255) / 256, 256, 0, stream>>>(wcatT + (size_t)5128 * 1024, 120 * 1024);

    gemm_bt<0><<<dim3(NCAT / 128, MROWS / 128), 256, 0, stream>>>(x_bf, wcatT, pre, MROWS, NCAT, DIM);

    conv_silu<<<MROWS, 256, 0, stream>>>(pre, qbuf, cqw, cqb, 1.0f, 0);
    conv_silu<<<MROWS, 256, 0, stream>>>(pre, kbuf, ckw, ckb, 0.08838834764831845f, 1024);
    conv_silu<<<MROWS, 256, 0, stream>>>(pre, vbuf, cvw, cvb, 1.0f, 2048);

    scan_kernel<<<128, 128, 0, stream>>>(qbuf, kbuf, vbuf, pre, ba, bb, obuf);

    ln_gate<<<MROWS, 256, 0, stream>>>(obuf, pre, lng, lnb, o2buf);

    gemm_bt<1><<<dim3(DIM / 128, MROWS / 128), 256, 0, stream>>>(o2buf, woT, d_out, MROWS, DIM, DIM);
}

// Round 9
// 979.590 us; speedup vs baseline: 1.2504x; 1.2504x over previous
//
#include <hip/hip_runtime.h>

typedef unsigned short u16;
typedef __attribute__((ext_vector_type(8))) unsigned short ushort8;
typedef __attribute__((ext_vector_type(4))) unsigned short ushort4v;
typedef __attribute__((ext_vector_type(8))) short bf16x8;
typedef __attribute__((ext_vector_type(4))) float f32x4;

#define LB    2048
#define DIM   1024
#define NCAT  5248
#define MROWS 8192
#define G     16
#define NG    (LB / G)

__device__ __forceinline__ float b2f(u16 u) {
    unsigned int x = ((unsigned int)u) << 16;
    return __builtin_bit_cast(float, x);
}
__device__ __forceinline__ u16 f2b(float f) {
    unsigned int u = __builtin_bit_cast(unsigned int, f);
    u = u + 0x7FFFu + ((u >> 16) & 1u);
    return (u16)(u >> 16);
}
__device__ __forceinline__ float sigm(float x) { return 1.0f / (1.0f + __expf(-x)); }

// DPP cross-lane add: x + x[lane ^ pattern], full-rate VALU.
template <int CTRL>
__device__ __forceinline__ float dpp_addf(float x) {
    int y = __builtin_amdgcn_update_dpp(0, __builtin_bit_cast(int, x), CTRL, 0xF, 0xF, true);
    return x + __builtin_bit_cast(float, y);
}
__device__ __forceinline__ float sum8_dpp(float x) {
    x = dpp_addf<0xB1>(x);   // xor 1
    x = dpp_addf<0x4E>(x);   // xor 2
    x = dpp_addf<0x141>(x);  // xor 4 (row_half_mirror)
    return x;
}

// async global->LDS, 16B per lane; LDS dest = wave-uniform base + lane*16.
__device__ __forceinline__ void gload_lds16(const u16* g, u16* l) {
    __builtin_amdgcn_global_load_lds((const __attribute__((address_space(1))) void*)g,
                                     (__attribute__((address_space(3))) void*)l, 16, 0, 0);
}

// ---------------- elementwise prep ----------------
__global__ void f32_to_bf16(const float* __restrict__ src, u16* __restrict__ dst, int n) {
    int i = (blockIdx.x * 256 + threadIdx.x) * 4;
    if (i >= n) return;
    float4 v = *(const float4*)(src + i);
    ushort4v u;
    u[0] = f2b(v.x); u[1] = f2b(v.y); u[2] = f2b(v.z); u[3] = f2b(v.w);
    *(ushort4v*)(dst + i) = u;
}

// src [1024, cols] f32  ->  dst[c*1024 + r] bf16   (grid: (cols, 4), block 256)
__global__ void transpose_f32_bf16(const float* __restrict__ src, u16* __restrict__ dst, int cols) {
    const int cidx = blockIdx.x;
    const int r = blockIdx.y * 256 + threadIdx.x;
    dst[(size_t)cidx * 1024 + r] = f2b(src[(size_t)r * cols + cidx]);
}

__global__ void fill_zero_u16(u16* __restrict__ dst, int n) {
    int i = blockIdx.x * 256 + threadIdx.x;
    if (i < n) dst[i] = 0;
}

// ---------------- bf16 MFMA GEMM (m97 structure):  C[M,N] = A[M,K] * Bt[N,K]^T ----------------
// Linear LDS tiles [128][32] u16 (no padding: global_load_lds writes base+lane*16).
template <int OUT_IS_F32>
__global__ __launch_bounds__(256) void gemm_bt(const u16* __restrict__ A,
                                               const u16* __restrict__ Bt,
                                               void* __restrict__ Cv,
                                               int M, int N, int K) {
    __shared__ u16 lds_a[128 * 32];
    __shared__ u16 lds_b[128 * 32];
    const int tid = threadIdx.x;
    const int m0 = blockIdx.y * 128;
    const int n0 = blockIdx.x * 128;
    const int w = tid >> 6;
    const int l = tid & 63;
    const int wm = w >> 1, wn = w & 1;
    const int lr = l & 15, kg = l >> 4;

    f32x4 acc[4][4];
#pragma unroll
    for (int m = 0; m < 4; ++m)
#pragma unroll
        for (int n = 0; n < 4; ++n)
            acc[m][n] = f32x4{0.f, 0.f, 0.f, 0.f};

    // staging: wave w stages rows [w*32, w*32+32); lane i -> row i>>2, col (i&3)*8.
    const int srow = (l >> 2);
    const int scol = (l & 3) * 8;
    (void)srow;

    for (int kt = 0; kt < K; kt += 32) {
#pragma unroll
        for (int ld = 0; ld < 2; ++ld) {
            const int row = w * 32 + ld * 16 + (l >> 2);
            gload_lds16(A + (size_t)(m0 + row) * K + kt + scol, &lds_a[(w * 32 + ld * 16) * 32]);
            gload_lds16(Bt + (size_t)(n0 + row) * K + kt + scol, &lds_b[(w * 32 + ld * 16) * 32]);
        }
        __syncthreads();
        bf16x8 af[4], bfv[4];
#pragma unroll
        for (int m = 0; m < 4; ++m)
            af[m] = *(const bf16x8*)&lds_a[(wm * 64 + m * 16 + lr) * 32 + kg * 8];
#pragma unroll
        for (int n = 0; n < 4; ++n)
            bfv[n] = *(const bf16x8*)&lds_b[(wn * 64 + n * 16 + lr) * 32 + kg * 8];
#pragma unroll
        for (int m = 0; m < 4; ++m)
#pragma unroll
            for (int n = 0; n < 4; ++n)
                acc[m][n] = __builtin_amdgcn_mfma_f32_16x16x32_bf16(af[m], bfv[n], acc[m][n], 0, 0, 0);
        __syncthreads();
    }

#pragma unroll
    for (int m = 0; m < 4; ++m) {
#pragma unroll
        for (int n = 0; n < 4; ++n) {
            const int col = n0 + wn * 64 + n * 16 + lr;
#pragma unroll
            for (int j = 0; j < 4; ++j) {
                const int row = m0 + wm * 64 + m * 16 + kg * 4 + j;
                if (OUT_IS_F32)
                    ((float*)Cv)[(size_t)row * N + col] = acc[m][n][j];
                else
                    ((u16*)Cv)[(size_t)row * N + col] = f2b(acc[m][n][j]);
            }
        }
    }
}

// ---------------- causal depthwise conv (K=4) + bias + SiLU (+scale) ----------------
__global__ __launch_bounds__(256) void conv_silu(const u16* __restrict__ pre,
                                                 u16* __restrict__ dst,
                                                 const float* __restrict__ w,
                                                 const float* __restrict__ bias,
                                                 float scale, int col_off) {
    const int row = blockIdx.x;       // b*L + l
    const int l = row & (LB - 1);
    const int ch = threadIdx.x * 4;
    const float4* wv = (const float4*)(w + ch * 4);
    float wt[4][4];
#pragma unroll
    for (int c = 0; c < 4; ++c) {
        float4 t = wv[c];
        wt[c][0] = t.x; wt[c][1] = t.y; wt[c][2] = t.z; wt[c][3] = t.w;
    }
    float acc[4] = {bias[ch + 0], bias[ch + 1], bias[ch + 2], bias[ch + 3]};
#pragma unroll
    for (int dd = 0; dd < 4; ++dd) {
        if (l - 3 + dd >= 0) {
            ushort4v vv = *(const ushort4v*)(pre + (size_t)(row - 3 + dd) * NCAT + col_off + ch);
#pragma unroll
            for (int c = 0; c < 4; ++c) acc[c] += b2f(vv[c]) * wt[c][dd];
        }
    }
    ushort4v outv;
#pragma unroll
    for (int c = 0; c < 4; ++c) {
        float a = acc[c];
        outv[c] = f2b(a * sigm(a) * scale);
    }
    *(ushort4v*)(dst + (size_t)row * DIM + ch) = outv;
}

// ---------------- sequential delta-rule scan ----------------
// 256 blocks (XCD-swizzled over b*h*vchunk), 128 threads.
// thread (r = tid>>3, c = tid&7): owns S[v0+r][c*16 .. c*16+15] in registers.
// k/q/v/a/b staged per G=16 steps through double-buffered LDS; DEPTH-4 rotating
// register prefetch hides LDS latency; DPP row reductions.
__global__ __launch_bounds__(128) void scan_kernel(const u16* __restrict__ qb,
                                                   const u16* __restrict__ kb,
                                                   const u16* __restrict__ vb,
                                                   const u16* __restrict__ pre,
                                                   const float* __restrict__ ba,
                                                   const float* __restrict__ bb,
                                                   float* __restrict__ o) {
    // XCD swizzle: XCD = blockIdx % 8; the 8 blocks sharing (b,h) k/q sit on one XCD.
    const int bid = blockIdx.x;                 // 0..255
    const int vc = (bid >> 3) & 7;              // varies within an XCD
    const int bh = (bid & 7) * 4 + (bid >> 6);  // constant groups of 8 per XCD
    const int h = bh & 7;
    const int b = bh >> 3;

    const int tid = threadIdx.x;
    const int r = tid >> 3;     // 0..15  (v-row within chunk)
    const int c = tid & 7;      // 0..7   (16-col slice of k-dim)
    const int k0 = c * 16;
    const int v0 = vc * 16;
    const size_t row0 = (size_t)b * LB;

    __shared__ u16 k_lds[2][G][128];
    __shared__ u16 q_lds[2][G][128];
    __shared__ float v_ldsf[2][G][16];
    __shared__ float a_ldsf[2][G][16];   // sigmoid already applied
    __shared__ float b_ldsf[2][G];       // sigmoid already applied

    const float bbv = bb[h];

    // staging roles
    const int st_t = tid >> 3;          // k/q: step index 0..15
    const int st_c = tid & 7;           // k/q: 16-elem chunk
    const u16* kgp = kb + row0 * DIM + h * 128 + st_c * 16;
    const u16* qgp = qb + row0 * DIM + h * 128 + st_c * 16;
    const u16* vgp = vb + row0 * DIM + h * 128 + v0 + (tid & 1) * 8;    // tid<32
    const u16* agp = pre + row0 * NCAT + 3072 + h * 128 + v0 + (tid & 1) * 8; // 32<=tid<64
    const u16* bgp = pre + row0 * NCAT + 5120 + h;                       // 64<=tid<80
    float* op = o + row0 * DIM + h * 128 + v0 + r;

    float baf[8];
    if (tid >= 32 && tid < 64) {
        const float* bap = ba + h * 128 + v0 + (tid & 1) * 8;
#pragma unroll
        for (int j = 0; j < 8; ++j) baf[j] = bap[j];
    }

    ushort8 kst0, kst1, qst0, qst1, vst, ast;
    u16 bst;

    // depth-4 rotating prefetch slots (statically indexed in unrolled loop)
    ushort8 kpf0[4], kpf1[4], qpf0[4], qpf1[4];
    float vpf[4], apf[4], bpf[4];

#define STAGE_LOAD(gl) do {                                                     \
        const size_t rk = (size_t)((gl) * G + st_t) * DIM;                      \
        kst0 = *(const ushort8*)(kgp + rk);                                     \
        kst1 = *(const ushort8*)(kgp + rk + 8);                                 \
        qst0 = *(const ushort8*)(qgp + rk);                                     \
        qst1 = *(const ushort8*)(qgp + rk + 8);                                 \
        if (tid < 32) {                                                         \
            vst = *(const ushort8*)(vgp + (size_t)((gl) * G + (tid >> 1)) * DIM); \
        } else if (tid < 64) {                                                  \
            ast = *(const ushort8*)(agp + (size_t)((gl) * G + ((tid - 32) >> 1)) * NCAT); \
        } else if (tid < 80) {                                                  \
            bst = bgp[(size_t)((gl) * G + (tid - 64)) * NCAT];                  \
        }                                                                       \
    } while (0)

#define STAGE_WRITE(bufi) do {                                                  \
        *(ushort8*)&k_lds[bufi][st_t][st_c * 16] = kst0;                        \
        *(ushort8*)&k_lds[bufi][st_t][st_c * 16 + 8] = kst1;                    \
        *(ushort8*)&q_lds[bufi][st_t][st_c * 16] = qst0;                        \
        *(ushort8*)&q_lds[bufi][st_t][st_c * 16 + 8] = qst1;                    \
        if (tid < 32) {                                                         \
            float* d = &v_ldsf[bufi][tid >> 1][(tid & 1) * 8];                  \
            _Pragma("unroll") for (int j = 0; j < 8; ++j) d[j] = b2f(vst[j]);   \
        } else if (tid < 64) {                                                  \
            float* d = &a_ldsf[bufi][(tid - 32) >> 1][(tid & 1) * 8];           \
            _Pragma("unroll") for (int j = 0; j < 8; ++j) d[j] = sigm(b2f(ast[j]) + baf[j]); \
        } else if (tid < 80) {                                                  \
            b_ldsf[bufi][tid - 64] = sigm(b2f(bst) + bbv);                      \
        }                                                                       \
    } while (0)

#define PREF(bufi, tt, sl) do {                                                 \
        kpf0[sl] = *(const ushort8*)&k_lds[bufi][tt][k0];                       \
        kpf1[sl] = *(const ushort8*)&k_lds[bufi][tt][k0 + 8];                   \
        qpf0[sl] = *(const ushort8*)&q_lds[bufi][tt][k0];                       \
        qpf1[sl] = *(const ushort8*)&q_lds[bufi][tt][k0 + 8];                   \
        vpf[sl] = v_ldsf[bufi][tt][r];                                          \
        apf[sl] = a_ldsf[bufi][tt][r];                                          \
        bpf[sl] = b_ldsf[bufi][tt];                                             \
    } while (0)

    float S[16];
#pragma unroll
    for (int j = 0; j < 16; ++j) S[j] = 0.f;

    // prologue: fill buffer 0, prefetch steps 0..3
    STAGE_LOAD(0);
    STAGE_WRITE(0);
    __syncthreads();
    PREF(0, 0, 0); PREF(0, 1, 1); PREF(0, 2, 2); PREF(0, 3, 3);

    for (int g = 0; g < NG; ++g) {
        const int buf = g & 1;
        const int gn = (g + 1 < NG) ? g + 1 : g;   // clamp: last group reloads itself (unused)
        STAGE_LOAD(gn);                            // global loads in flight during compute

#pragma unroll
        for (int t = 0; t < G; ++t) {
            const int sl = t & 3;

            float kf[16], qf[16];
#pragma unroll
            for (int j = 0; j < 8; ++j) {
                kf[j] = b2f(kpf0[sl][j]); kf[8 + j] = b2f(kpf1[sl][j]);
                qf[j] = b2f(qpf0[sl][j]); qf[8 + j] = b2f(qpf1[sl][j]);
            }
            const float vcf = vpf[sl];
            const float acf = apf[sl];
            const float bcf = bpf[sl];

            // refill this slot for step t+4 (slot free after the reads above)
            if (t < G - 4) PREF(buf, t + 4, sl);

            // err = S . k  (partial over 16 cols, reduce across 8 lanes via DPP)
            float e0 = 0.f, e1 = 0.f, e2 = 0.f, e3 = 0.f;
#pragma unroll
            for (int j = 0; j < 4; ++j) {
                e0 += S[j] * kf[j];
                e1 += S[4 + j] * kf[4 + j];
                e2 += S[8 + j] * kf[8 + j];
                e3 += S[12 + j] * kf[12 + j];
            }
            float e = sum8_dpp((e0 + e1) + (e2 + e3));
            const float be = bcf * (e - vcf);

            // S = a*S - be*k ;  po = S_new . q
            float p0 = 0.f, p1 = 0.f, p2 = 0.f, p3 = 0.f;
#pragma unroll
            for (int j = 0; j < 4; ++j) {
                S[j] = acf * S[j] - be * kf[j];                p0 += S[j] * qf[j];
                S[4 + j] = acf * S[4 + j] - be * kf[4 + j];    p1 += S[4 + j] * qf[4 + j];
                S[8 + j] = acf * S[8 + j] - be * kf[8 + j];    p2 += S[8 + j] * qf[8 + j];
                S[12 + j] = acf * S[12 + j] - be * kf[12 + j]; p3 += S[12 + j] * qf[12 + j];
            }
            float po = sum8_dpp((p0 + p1) + (p2 + p3));
            if (c == 0) op[(size_t)(g * G + t) * DIM] = po;
        }

        STAGE_WRITE(buf ^ 1);   // waits vmcnt for staged regs; buffer free since group g-1
        __syncthreads();
        const int nb = buf ^ 1;
        PREF(nb, 0, 0); PREF(nb, 1, 1); PREF(nb, 2, 2); PREF(nb, 3, 3);
    }
#undef STAGE_LOAD
#undef STAGE_WRITE
#undef PREF
}

// ---------------- LayerNorm(DV) + sigmoid gate -> bf16 ----------------
__global__ __launch_bounds__(256) void ln_gate(const float* __restrict__ o,
                                               const u16* __restrict__ pre,
                                               const float* __restrict__ ln_g,
                                               const float* __restrict__ ln_b,
                                               u16* __restrict__ o2) {
    const int row = blockIdx.x;
    const int tid = threadIdx.x;
    const int h = tid >> 5;
    const int lg = tid & 31;
    const int d0 = lg * 4;
    float4 x = *(const float4*)(o + (size_t)row * DIM + h * 128 + d0);
    float s = x.x + x.y + x.z + x.w;
    float ss = x.x * x.x + x.y * x.y + x.z * x.z + x.w * x.w;
#pragma unroll
    for (int m = 1; m <= 16; m <<= 1) {
        s += __shfl_xor(s, m);
        ss += __shfl_xor(ss, m);
    }
    const float mu = s * (1.f / 128.f);
    const float var = ss * (1.f / 128.f) - mu * mu;
    const float inv = rsqrtf(var + 1e-5f);
    ushort4v gp = *(const ushort4v*)(pre + (size_t)row * NCAT + 4096 + h * 128 + d0);
    float4 lg4 = *(const float4*)(ln_g + d0);
    float4 lb4 = *(const float4*)(ln_b + d0);
    float xv[4] = {x.x, x.y, x.z, x.w};
    float gv[4] = {lg4.x, lg4.y, lg4.z, lg4.w};
    float bv[4] = {lb4.x, lb4.y, lb4.z, lb4.w};
    ushort4v outv;
#pragma unroll
    for (int q = 0; q < 4; ++q) {
        float y = (xv[q] - mu) * inv * gv[q] + bv[q];
        y *= sigm(b2f(gp[q]));
        outv[q] = f2b(y);
    }
    *(ushort4v*)(o2 + (size_t)row * DIM + h * 128 + d0) = outv;
}

extern "C" void kernel_launch(void* const* d_in, const int* in_sizes, int n_in,
                              void* d_out, int out_size, void* d_ws, size_t ws_size,
                              hipStream_t stream) {
    const float* x   = (const float*)d_in[0];
    const float* Wq  = (const float*)d_in[1];
    const float* Wk  = (const float*)d_in[2];
    const float* Wv  = (const float*)d_in[3];
    const float* Wa  = (const float*)d_in[4];
    const float* ba  = (const float*)d_in[5];
    const float* Wb  = (const float*)d_in[6];
    const float* bb  = (const float*)d_in[7];
    const float* Wg  = (const float*)d_in[8];
    const float* Wo  = (const float*)d_in[9];
    const float* cqw = (const float*)d_in[10];
    const float* cqb = (const float*)d_in[11];
    const float* ckw = (const float*)d_in[12];
    const float* ckb = (const float*)d_in[13];
    const float* cvw = (const float*)d_in[14];
    const float* cvb = (const float*)d_in[15];
    const float* lng = (const float*)d_in[16];
    const float* lnb = (const float*)d_in[17];

    const size_t NEED = (size_t)MROWS * DIM * 2
                      + (size_t)NCAT * DIM * 2
                      + (size_t)DIM * DIM * 2
                      + (size_t)MROWS * NCAT * 2
                      + 3 * (size_t)MROWS * DIM * 2
                      + (size_t)MROWS * DIM * 4
                      + (size_t)MROWS * DIM * 2;
    if (ws_size < NEED) return;

    char* p = (char*)d_ws;
    u16* x_bf  = (u16*)p; p += (size_t)MROWS * DIM * 2;
    u16* wcatT = (u16*)p; p += (size_t)NCAT * DIM * 2;
    u16* woT   = (u16*)p; p += (size_t)DIM * DIM * 2;
    u16* pre   = (u16*)p; p += (size_t)MROWS * NCAT * 2;
    u16* qbuf  = (u16*)p; p += (size_t)MROWS * DIM * 2;
    u16* kbuf  = (u16*)p; p += (size_t)MROWS * DIM * 2;
    u16* vbuf  = (u16*)p; p += (size_t)MROWS * DIM * 2;
    float* obuf = (float*)p; p += (size_t)MROWS * DIM * 4;
    u16* o2buf = (u16*)p;

    f32_to_bf16<<<MROWS * DIM / 1024, 256, 0, stream>>>(x, x_bf, MROWS * DIM);
    transpose_f32_bf16<<<dim3(1024, 4), 256, 0, stream>>>(Wq, wcatT + 0 * 1024 * 1024, 1024);
    transpose_f32_bf16<<<dim3(1024, 4), 256, 0, stream>>>(Wk, wcatT + 1 * 1024 * 1024, 1024);
    transpose_f32_bf16<<<dim3(1024, 4), 256, 0, stream>>>(Wv, wcatT + 2 * 1024 * 1024, 1024);
    transpose_f32_bf16<<<dim3(1024, 4), 256, 0, stream>>>(Wa, wcatT + 3 * 1024 * 1024, 1024);
    transpose_f32_bf16<<<dim3(1024, 4), 256, 0, stream>>>(Wg, wcatT + 4 * 1024 * 1024, 1024);
    transpose_f32_bf16<<<dim3(8, 4), 256, 0, stream>>>(Wb, wcatT + (size_t)5120 * 1024, 8);
    transpose_f32_bf16<<<dim3(1024, 4), 256, 0, stream>>>(Wo, woT, 1024);
    fill_zero_u16<<<(120 * 1024 + 255) / 256, 256, 0, stream>>>(wcatT + (size_t)5128 * 1024, 120 * 1024);

    gemm_bt<0><<<dim3(NCAT / 128, MROWS / 128), 256, 0, stream>>>(x_bf, wcatT, pre, MROWS, NCAT, DIM);

    conv_silu<<<MROWS, 256, 0, stream>>>(pre, qbuf, cqw, cqb, 1.0f, 0);
    conv_silu<<<MROWS, 256, 0, stream>>>(pre, kbuf, ckw, ckb, 0.08838834764831845f, 1024);
    conv_silu<<<MROWS, 256, 0, stream>>>(pre, vbuf, cvw, cvb, 1.0f, 2048);

    scan_kernel<<<256, 128, 0, stream>>>(qbuf, kbuf, vbuf, pre, ba, bb, obuf);

    ln_gate<<<MROWS, 256, 0, stream>>>(obuf, pre, lng, lnb, o2buf);

    gemm_bt<1><<<dim3(DIM / 128, MROWS / 128), 256, 0, stream>>>(o2buf, woT, d_out, MROWS, DIM, DIM);
}